// Round 1
// baseline (244.488 us; speedup 1.0000x reference)
//
#include <hip/hip_runtime.h>

typedef float  f32x4  __attribute__((ext_vector_type(4)));
typedef short  bf16x8 __attribute__((ext_vector_type(8)));
typedef unsigned short u16;

#define NN   20000
#define NE   200000
#define DIM  128
#define EDIM 64
#define HID  256
#define KIN  192   // DIM + EDIM

__device__ __forceinline__ u16 f2b(float f) {
  unsigned u = __float_as_uint(f);
  u += 0x7FFFu + ((u >> 16) & 1u);   // round-to-nearest-even
  return (u16)(u >> 16);
}

// ---------------------------------------------------------------- prep:
// transpose weights to bf16 N-major so MFMA B-fragments are contiguous 16B.
__global__ void prep_kernel(const float* __restrict__ mW1, const float* __restrict__ mW2,
                            const float* __restrict__ sW1, const float* __restrict__ sW2,
                            u16* __restrict__ W1T, u16* __restrict__ W2T,
                            u16* __restrict__ S1T, u16* __restrict__ S2T) {
  int t  = blockIdx.x * blockDim.x + threadIdx.x;
  int nt = gridDim.x * blockDim.x;
  for (int i = t; i < KIN * HID; i += nt) { int k = i / HID, n = i % HID; W1T[n * KIN + k] = f2b(mW1[i]); }
  for (int i = t; i < HID * DIM; i += nt) { int k = i / DIM, n = i % DIM; W2T[n * HID + k] = f2b(mW2[i]); }
  for (int i = t; i < DIM * HID; i += nt) { int k = i / HID, n = i % HID; S1T[n * DIM + k] = f2b(sW1[i]); }
  for (int i = t; i < HID * DIM; i += nt) { int k = i / DIM, n = i % DIM; S2T[n * HID + k] = f2b(sW2[i]); }
}

// ---------------------------------------------------------------- edge MLP
// 64 edges/block, 4 waves. LDS union: X[64][192] bf16 then hid[64][256] bf16.
// XOR swizzle byte ^= (row&7)<<4 on all LDS rows (row strides are 128B mults).
__global__ __launch_bounds__(256) void edge_kernel(
    const float* __restrict__ H, const int* __restrict__ EI,
    const float* __restrict__ EA,
    const u16* __restrict__ W1T, const float* __restrict__ b1p,
    const u16* __restrict__ W2T, const float* __restrict__ b2p,
    float* __restrict__ agg) {
  __shared__ int src_s[64];
  __shared__ int dst_s[64];
  __shared__ u16 smem[64 * HID];   // 32 KB union

  const int tid = threadIdx.x;
  const int e0  = blockIdx.x * 64;
  if (tid < 64)       src_s[tid]      = EI[e0 + tid];
  else if (tid < 128) dst_s[tid - 64] = EI[NE + e0 + tid - 64];
  __syncthreads();

  // stage H[src] -> X cols 0..127 (64 rows x 32 float4, 32 lanes/row)
  #pragma unroll
  for (int i = 0; i < 8; ++i) {
    int idx = tid + i * 256;
    int row = idx >> 5, c4 = idx & 31;
    const float4 v = reinterpret_cast<const float4*>(H + (size_t)src_s[row] * DIM)[c4];
    int by = (c4 * 8) ^ ((row & 7) << 4);
    ushort4 o; o.x = f2b(v.x); o.y = f2b(v.y); o.z = f2b(v.z); o.w = f2b(v.w);
    *reinterpret_cast<ushort4*>(&smem[row * KIN + (by >> 1)]) = o;
  }
  // stage edge_attr -> X cols 128..191 (64 rows x 16 float4)
  #pragma unroll
  for (int i = 0; i < 4; ++i) {
    int idx = tid + i * 256;
    int row = idx >> 4, c4 = idx & 15;
    const float4 v = reinterpret_cast<const float4*>(EA + (size_t)(e0 + row) * EDIM)[c4];
    int by = (256 + c4 * 8) ^ ((row & 7) << 4);
    ushort4 o; o.x = f2b(v.x); o.y = f2b(v.y); o.z = f2b(v.z); o.w = f2b(v.w);
    *reinterpret_cast<ushort4*>(&smem[row * KIN + (by >> 1)]) = o;
  }
  __syncthreads();

  const int wv = tid >> 6, lane = tid & 63;
  const int lr = lane & 15, lg = lane >> 4;
  const f32x4 zero = {0.f, 0.f, 0.f, 0.f};

  // ---- layer 1: [64,192] @ [192,256], wave owns 64 cols
  const int n0 = wv * 64;
  f32x4 acc[4][4];
  #pragma unroll
  for (int m = 0; m < 4; ++m)
    #pragma unroll
    for (int n = 0; n < 4; ++n) acc[m][n] = zero;
  float bias1[4];
  #pragma unroll
  for (int n = 0; n < 4; ++n) bias1[n] = b1p[n0 + n * 16 + lr];

  #pragma unroll
  for (int kt = 0; kt < 6; ++kt) {
    bf16x8 af[4], bf[4];
    #pragma unroll
    for (int m = 0; m < 4; ++m) {
      int row = m * 16 + lr;
      int by  = (kt * 64 + lg * 16) ^ ((row & 7) << 4);
      af[m] = *reinterpret_cast<const bf16x8*>(&smem[row * KIN + (by >> 1)]);
    }
    #pragma unroll
    for (int n = 0; n < 4; ++n) {
      int nabs = n0 + n * 16 + lr;
      bf[n] = *reinterpret_cast<const bf16x8*>(&W1T[nabs * KIN + kt * 32 + lg * 8]);
    }
    #pragma unroll
    for (int m = 0; m < 4; ++m)
      #pragma unroll
      for (int n = 0; n < 4; ++n)
        acc[m][n] = __builtin_amdgcn_mfma_f32_16x16x32_bf16(af[m], bf[n], acc[m][n], 0, 0, 0);
  }
  __syncthreads();   // X reads done; reuse smem for hid

  // relu + bias -> hid[64][256] bf16 (swizzled)
  #pragma unroll
  for (int m = 0; m < 4; ++m)
    #pragma unroll
    for (int n = 0; n < 4; ++n)
      #pragma unroll
      for (int r = 0; r < 4; ++r) {
        int row = m * 16 + lg * 4 + r;
        int col = n0 + n * 16 + lr;
        float v = acc[m][n][r] + bias1[n];
        v = fmaxf(v, 0.0f);
        int by = (col * 2) ^ ((row & 7) << 4);
        smem[row * HID + (by >> 1)] = f2b(v);
      }
  __syncthreads();

  // ---- layer 2: [64,256] @ [256,128], wave owns 32 cols
  const int n0b = wv * 32;
  f32x4 acc2[4][2];
  #pragma unroll
  for (int m = 0; m < 4; ++m) { acc2[m][0] = zero; acc2[m][1] = zero; }
  float bias2[2];
  #pragma unroll
  for (int n = 0; n < 2; ++n) bias2[n] = b2p[n0b + n * 16 + lr];

  #pragma unroll
  for (int kt = 0; kt < 8; ++kt) {
    bf16x8 af[4], bf[2];
    #pragma unroll
    for (int m = 0; m < 4; ++m) {
      int row = m * 16 + lr;
      int by  = (kt * 64 + lg * 16) ^ ((row & 7) << 4);
      af[m] = *reinterpret_cast<const bf16x8*>(&smem[row * HID + (by >> 1)]);
    }
    #pragma unroll
    for (int n = 0; n < 2; ++n) {
      int nabs = n0b + n * 16 + lr;
      bf[n] = *reinterpret_cast<const bf16x8*>(&W2T[nabs * HID + kt * 32 + lg * 8]);
    }
    #pragma unroll
    for (int m = 0; m < 4; ++m)
      #pragma unroll
      for (int n = 0; n < 2; ++n)
        acc2[m][n] = __builtin_amdgcn_mfma_f32_16x16x32_bf16(af[m], bf[n], acc2[m][n], 0, 0, 0);
  }

  // scatter-add messages to agg[dst]
  #pragma unroll
  for (int m = 0; m < 4; ++m)
    #pragma unroll
    for (int n = 0; n < 2; ++n) {
      int col = n0b + n * 16 + lr;
      float bb = bias2[n];
      #pragma unroll
      for (int r = 0; r < 4; ++r) {
        int row = m * 16 + lg * 4 + r;
        int d   = dst_s[row];
        atomicAdd(&agg[(size_t)d * DIM + col], acc2[m][n][r] + bb);
      }
    }
}

// ---------------------------------------------------------------- self MLP
// 64 nodes/block; x = (1+eps)*H + agg; out f32.
__global__ __launch_bounds__(256) void self_kernel(
    const float* __restrict__ H, const float* __restrict__ agg,
    const float* __restrict__ epsp,
    const u16* __restrict__ S1T, const float* __restrict__ b1p,
    const u16* __restrict__ S2T, const float* __restrict__ b2p,
    float* __restrict__ out) {
  __shared__ u16 smem[64 * HID];   // union X2[64][128] / hid[64][256]
  const int tid = threadIdx.x;
  const int r0  = blockIdx.x * 64;
  const float sc = 1.0f + epsp[0];

  #pragma unroll
  for (int i = 0; i < 8; ++i) {
    int idx = tid + i * 256;
    int row = idx >> 5, c4 = idx & 31;
    int gr = r0 + row; gr = gr < NN ? gr : NN - 1;
    const float4 h = reinterpret_cast<const float4*>(H   + (size_t)gr * DIM)[c4];
    const float4 a = reinterpret_cast<const float4*>(agg + (size_t)gr * DIM)[c4];
    ushort4 o;
    o.x = f2b(sc * h.x + a.x); o.y = f2b(sc * h.y + a.y);
    o.z = f2b(sc * h.z + a.z); o.w = f2b(sc * h.w + a.w);
    int by = (c4 * 8) ^ ((row & 7) << 4);
    *reinterpret_cast<ushort4*>(&smem[row * DIM + (by >> 1)]) = o;
  }
  __syncthreads();

  const int wv = tid >> 6, lane = tid & 63;
  const int lr = lane & 15, lg = lane >> 4;
  const f32x4 zero = {0.f, 0.f, 0.f, 0.f};

  // ---- layer 1: [64,128] @ [128,256]
  const int n0 = wv * 64;
  f32x4 acc[4][4];
  #pragma unroll
  for (int m = 0; m < 4; ++m)
    #pragma unroll
    for (int n = 0; n < 4; ++n) acc[m][n] = zero;
  float bias1[4];
  #pragma unroll
  for (int n = 0; n < 4; ++n) bias1[n] = b1p[n0 + n * 16 + lr];

  #pragma unroll
  for (int kt = 0; kt < 4; ++kt) {
    bf16x8 af[4], bf[4];
    #pragma unroll
    for (int m = 0; m < 4; ++m) {
      int row = m * 16 + lr;
      int by  = (kt * 64 + lg * 16) ^ ((row & 7) << 4);
      af[m] = *reinterpret_cast<const bf16x8*>(&smem[row * DIM + (by >> 1)]);
    }
    #pragma unroll
    for (int n = 0; n < 4; ++n) {
      int nabs = n0 + n * 16 + lr;
      bf[n] = *reinterpret_cast<const bf16x8*>(&S1T[nabs * DIM + kt * 32 + lg * 8]);
    }
    #pragma unroll
    for (int m = 0; m < 4; ++m)
      #pragma unroll
      for (int n = 0; n < 4; ++n)
        acc[m][n] = __builtin_amdgcn_mfma_f32_16x16x32_bf16(af[m], bf[n], acc[m][n], 0, 0, 0);
  }
  __syncthreads();

  #pragma unroll
  for (int m = 0; m < 4; ++m)
    #pragma unroll
    for (int n = 0; n < 4; ++n)
      #pragma unroll
      for (int r = 0; r < 4; ++r) {
        int row = m * 16 + lg * 4 + r;
        int col = n0 + n * 16 + lr;
        float v = acc[m][n][r] + bias1[n];
        v = fmaxf(v, 0.0f);
        int by = (col * 2) ^ ((row & 7) << 4);
        smem[row * HID + (by >> 1)] = f2b(v);
      }
  __syncthreads();

  // ---- layer 2: [64,256] @ [256,128]
  const int n0b = wv * 32;
  f32x4 acc2[4][2];
  #pragma unroll
  for (int m = 0; m < 4; ++m) { acc2[m][0] = zero; acc2[m][1] = zero; }
  float bias2[2];
  #pragma unroll
  for (int n = 0; n < 2; ++n) bias2[n] = b2p[n0b + n * 16 + lr];

  #pragma unroll
  for (int kt = 0; kt < 8; ++kt) {
    bf16x8 af[4], bf[2];
    #pragma unroll
    for (int m = 0; m < 4; ++m) {
      int row = m * 16 + lr;
      int by  = (kt * 64 + lg * 16) ^ ((row & 7) << 4);
      af[m] = *reinterpret_cast<const bf16x8*>(&smem[row * HID + (by >> 1)]);
    }
    #pragma unroll
    for (int n = 0; n < 2; ++n) {
      int nabs = n0b + n * 16 + lr;
      bf[n] = *reinterpret_cast<const bf16x8*>(&S2T[nabs * HID + kt * 32 + lg * 8]);
    }
    #pragma unroll
    for (int m = 0; m < 4; ++m)
      #pragma unroll
      for (int n = 0; n < 2; ++n)
        acc2[m][n] = __builtin_amdgcn_mfma_f32_16x16x32_bf16(af[m], bf[n], acc2[m][n], 0, 0, 0);
  }

  #pragma unroll
  for (int m = 0; m < 4; ++m)
    #pragma unroll
    for (int n = 0; n < 2; ++n) {
      int col = n0b + n * 16 + lr;
      float bb = bias2[n];
      #pragma unroll
      for (int r = 0; r < 4; ++r) {
        int row = m * 16 + lg * 4 + r;
        int gr  = r0 + row;
        if (gr < NN) out[(size_t)gr * DIM + col] = acc2[m][n][r] + bb;
      }
    }
}

// ----------------------------------------------------------------
extern "C" void kernel_launch(void* const* d_in, const int* in_sizes, int n_in,
                              void* d_out, int out_size, void* d_ws, size_t ws_size,
                              hipStream_t stream) {
  const float* H   = (const float*)d_in[0];
  const int*   EI  = (const int*)  d_in[1];
  const float* EA  = (const float*)d_in[2];
  const float* EPS = (const float*)d_in[3];
  const float* mW1 = (const float*)d_in[4];
  const float* mb1 = (const float*)d_in[5];
  const float* mW2 = (const float*)d_in[6];
  const float* mb2 = (const float*)d_in[7];
  const float* sW1 = (const float*)d_in[8];
  const float* sb1 = (const float*)d_in[9];
  const float* sW2 = (const float*)d_in[10];
  const float* sb2 = (const float*)d_in[11];
  float* out = (float*)d_out;

  char* ws = (char*)d_ws;
  float* agg = (float*)ws;
  size_t off = (size_t)NN * DIM * 4;
  u16* W1T = (u16*)(ws + off); off += (size_t)HID * KIN * 2;
  u16* W2T = (u16*)(ws + off); off += (size_t)DIM * HID * 2;
  u16* S1T = (u16*)(ws + off); off += (size_t)HID * DIM * 2;
  u16* S2T = (u16*)(ws + off); off += (size_t)DIM * HID * 2;

  hipMemsetAsync(agg, 0, (size_t)NN * DIM * 4, stream);
  prep_kernel<<<96, 256, 0, stream>>>(mW1, mW2, sW1, sW2, W1T, W2T, S1T, S2T);
  edge_kernel<<<NE / 64, 256, 0, stream>>>(H, EI, EA, W1T, mb1, W2T, mb2, agg);
  self_kernel<<<(NN + 63) / 64, 256, 0, stream>>>(H, agg, EPS, S1T, sb1, S2T, sb2, out);
}